// Round 10
// baseline (923.057 us; speedup 1.0000x reference)
//
#include <hip/hip_runtime.h>
#include <hip/hip_bf16.h>

typedef unsigned short u16;
typedef unsigned int   u32;
typedef unsigned long long u64;
typedef long long      i64;
typedef __attribute__((ext_vector_type(8))) short short8;  // 8 bf16 raw
typedef __attribute__((ext_vector_type(4))) float f32x4;

#define HD 128   // hidden / input feature dim
#define OUTD 64  // final output dim
#define BIN_SHIFT 7      // 128 nodes per bin in two-phase fill

__device__ __forceinline__ float bf2f(u16 u){ union{u32 i; float f;} x; x.i=((u32)u)<<16; return x.f; }
__device__ __forceinline__ u16 f2bf(float f){ __hip_bfloat16 h=__float2bfloat16(f); return *reinterpret_cast<u16*>(&h); }

// 8-element bf16 fragment loader: fp32 source converts, bf16 source is direct.
__device__ __forceinline__ short8 load8(const float* p){
  f32x4 lo = *reinterpret_cast<const f32x4*>(p);
  f32x4 hi = *reinterpret_cast<const f32x4*>(p + 4);
  short8 r;
  #pragma unroll
  for (int j=0;j<4;j++){ r[j]=(short)f2bf(lo[j]); r[4+j]=(short)f2bf(hi[j]); }
  return r;
}
__device__ __forceinline__ short8 load8(const u16* p){
  return *reinterpret_cast<const short8*>(p);
}

// index fetch that handles int32-vs-int64 delivery (flag: 1 = int32, 0 = int64)
__device__ __forceinline__ int idx_at(const void* p, int i, int is32){
  return is32 ? ((const int*)p)[i] : (int)((const i64*)p)[i];
}

// ---- dtype detect: int64 buffers of nonneg values have all odd words == 0 --
__global__ void k_detect(const u32* __restrict__ w, int* __restrict__ flag, int npairs){
  int i = blockIdx.x*256 + threadIdx.x;
  if (i < npairs && w[2*i+1] != 0) atomicOr(flag, 1);   // nonzero odd word -> int32
}

// ---- sortedness check for batch -------------------------------------------
__global__ void k_check_sorted(const void* __restrict__ batch, const int* __restrict__ bflag,
                               int* __restrict__ sflag, int n){
  int i = blockIdx.x*256 + threadIdx.x;
  if (i < n-1){
    int is32 = *bflag;
    if (idx_at(batch, i, is32) > idx_at(batch, i+1, is32)) atomicOr(sflag, 1);
  }
}

// ---- zero-fill output (ws-too-small fallback signal) ----------------------
__global__ void k_zero_out(float* __restrict__ out, int n){
  int i = blockIdx.x*256 + threadIdx.x;
  if (i < n) out[i] = 0.f;
}

// ---- CSR build ------------------------------------------------------------
__global__ void k_count(const void* __restrict__ ei, const int* __restrict__ flag,
                        int* __restrict__ cnt, int E){
  int e = blockIdx.x*256 + threadIdx.x;
  if (e < E){
    int d = idx_at(ei, E + e, *flag);   // dst = row 1
    atomicAdd(&cnt[d], 1);
  }
}

__global__ void k_chunk_sums(const int* __restrict__ cnt, int* __restrict__ csum, int n){
  __shared__ int sd[256];
  int c=blockIdx.x, t=threadIdx.x;
  int base=c*1024+t*4, s=0;
  #pragma unroll
  for (int k=0;k<4;k++){ int i=base+k; if(i<n) s+=cnt[i]; }
  sd[t]=s; __syncthreads();
  for (int o=128;o>0;o>>=1){ if(t<o) sd[t]+=sd[t+o]; __syncthreads(); }
  if (t==0) csum[c]=sd[0];
}

// one-block exclusive scan of chunk totals (m <= 1024)
__global__ void k_scan_totals(int* csum, int m){
  __shared__ int sd[256];
  int t = threadIdx.x;
  int v[4]; int s=0;
  #pragma unroll
  for (int k=0;k<4;k++){ int i=t*4+k; v[k]=(i<m)?csum[i]:0; s+=v[k]; }
  sd[t]=s; __syncthreads();
  for (int o=1;o<256;o<<=1){ int x=(t>=o)?sd[t-o]:0; __syncthreads(); sd[t]+=x; __syncthreads(); }
  int pre = (t>0)?sd[t-1]:0;
  #pragma unroll
  for (int k=0;k<4;k++){ int i=t*4+k; if(i<m){ int vv=v[k]; csum[i]=pre; pre+=vv; } }
}

__global__ void k_scan_chunks(const int* __restrict__ cnt, const int* __restrict__ csum,
                              int* __restrict__ row_ptr, int* __restrict__ cursor,
                              float* __restrict__ dinv, int n, int total){
  __shared__ int sd[256];
  int c=blockIdx.x, t=threadIdx.x;
  int base=c*1024+t*4;
  int v[4], s=0;
  #pragma unroll
  for (int k=0;k<4;k++){ int i=base+k; v[k]=(i<n)?cnt[i]:0; s+=v[k]; }
  sd[t]=s; __syncthreads();
  for (int o=1;o<256;o<<=1){ int x=(t>=o)?sd[t-o]:0; __syncthreads(); sd[t]+=x; __syncthreads(); }
  int pre = csum[c] + ((t>0)?sd[t-1]:0);
  #pragma unroll
  for (int k=0;k<4;k++){
    int i=base+k;
    if (i<n){
      row_ptr[i]=pre; cursor[i]=pre;
      dinv[i]=rsqrtf((float)(v[k]+1));   // +1 self-loop; always >0
      pre+=v[k];
    }
  }
  if (c==0 && t==0) row_ptr[n]=total;
}

// ---- two-phase fill: phase 0 — init per-bin cursors from row_ptr ----------
__global__ void k_init_bincur(const int* __restrict__ row_ptr, int* __restrict__ bincur,
                              int nbins, int N){
  int b = blockIdx.x*256 + threadIdx.x;
  if (b < nbins){
    int node = b << BIN_SHIFT; if (node > N) node = N;
    bincur[b] = row_ptr[node];
  }
}

// ---- phase 1 — append (dst,src) u64 into the dst-bin's colv-region --------
// bin region ~17 KB: scattered 8 B writes stay in L2 until lines fill.
__global__ __launch_bounds__(256) void k_bin_edges(
    const void* __restrict__ ei, const int* __restrict__ flag,
    int* __restrict__ bincur, u64* __restrict__ pairs, int E)
{
  int e = blockIdx.x*256 + threadIdx.x;
  if (e < E){
    int is32 = *flag;
    int s = idx_at(ei, e, is32), d = idx_at(ei, E + e, is32);
    int pos = atomicAdd(&bincur[d>>BIN_SHIFT], 1);
    pairs[pos] = ((u64)(u32)d << 32) | (u32)s;
  }
}

// ---- phase 2 — exact per-dst scatter inside each bin ----------------------
// cursor slice (512 B) and colv region (~17 KB) are cache-resident.
__global__ __launch_bounds__(256) void k_scatter_bins(
    const u64* __restrict__ pairs, const int* __restrict__ row_ptr,
    int* __restrict__ cursor, int* __restrict__ colv, int N)
{
  int b = blockIdx.x;
  int n0 = b << BIN_SHIFT;        if (n0 > N) n0 = N;
  int n1 = (b+1) << BIN_SHIFT;    if (n1 > N) n1 = N;
  int lo = row_ptr[n0], hi = row_ptr[n1];
  for (int i = lo + threadIdx.x; i < hi; i += 256){
    u64 p = pairs[i];
    int s = (int)(u32)(p & 0xffffffffu), d = (int)(u32)(p >> 32);
    int pos = atomicAdd(&cursor[d], 1);
    colv[pos] = s;
  }
}

// ---- MFMA GEMM with dinv-scale epilogue: G = dinv ⊙ (X @ W) ---------------
template <typename TIN>
__global__ __launch_bounds__(256) void k_gemm_scale(
    const TIN* __restrict__ X, const float* __restrict__ W,
    const float* __restrict__ dinv, u16* __restrict__ Gout, int nrows)
{
  int lane = threadIdx.x & 63;
  int wv   = threadIdx.x >> 6;
  int n    = lane & 15, quad = lane >> 4;

  short8 bf[8][4];
  #pragma unroll
  for (int t=0;t<8;t++)
    #pragma unroll
    for (int c=0;c<4;c++)
      #pragma unroll
      for (int j=0;j<8;j++)
        bf[t][c][j] = (short)f2bf(W[(c*32 + quad*8 + j)*HD + t*16 + n]);

  int ntiles = (nrows+15)>>4;
  int stride = gridDim.x*4;
  for (int tile = blockIdx.x*4 + wv; tile < ntiles; tile += stride){
    int ra = tile*16 + n;                 // lane's A row (m = lane&15)
    if (ra >= nrows) ra = nrows-1;
    const TIN* xp = X + (size_t)ra*HD + quad*8;
    short8 a[4];
    #pragma unroll
    for (int c=0;c<4;c++) a[c] = load8(xp + c*32);

    f32x4 acc[8];
    #pragma unroll
    for (int t=0;t<8;t++) acc[t] = (f32x4){0.f,0.f,0.f,0.f};
    #pragma unroll
    for (int c=0;c<4;c++)
      #pragma unroll
      for (int t=0;t<8;t++)
        acc[t] = __builtin_amdgcn_mfma_f32_16x16x32_bf16(a[c], bf[t][c], acc[t], 0,0,0);

    float dv[4]; int rw[4];
    #pragma unroll
    for (int r=0;r<4;r++){
      int row = tile*16 + quad*4 + r;
      rw[r]=row; dv[r]=(row<nrows)?dinv[row]:0.f;
    }
    #pragma unroll
    for (int t=0;t<8;t++)
      #pragma unroll
      for (int r=0;r<4;r++){
        int row = rw[r];
        if (row < nrows)
          Gout[(size_t)row*HD + t*16 + n] = f2bf(dv[r]*acc[t][r]);
      }
  }
}

// ---- aggregation: h[i] = relu(dinv[i]*(g[i] + sum_{src} g[src]) + b) ------
// one wave per node; lane handles 2 features; unroll-8 for gather MLP.
__global__ __launch_bounds__(256) void k_aggregate(
    const u16* __restrict__ g, const int* __restrict__ row_ptr,
    const int* __restrict__ colv, const float* __restrict__ dinv,
    const float* __restrict__ bias, u16* __restrict__ h, int n)
{
  int node = blockIdx.x*4 + (threadIdx.x>>6);
  if (node >= n) return;
  int lane = threadIdx.x & 63;
  int off = lane*2;

  u32 u = *reinterpret_cast<const u32*>(g + (size_t)node*HD + off);   // self-loop term
  float ax = bf2f((u16)(u&0xffffu)), ay = bf2f((u16)(u>>16));

  int s = row_ptr[node], e = row_ptr[node+1];
  int i = s;
  for (; i+8<=e; i+=8){
    u32 v[8];
    #pragma unroll
    for (int j=0;j<8;j++){
      int sj = colv[i+j];
      v[j] = *reinterpret_cast<const u32*>(g+(size_t)sj*HD+off);
    }
    #pragma unroll
    for (int j=0;j<8;j++){
      ax += bf2f((u16)(v[j]&0xffffu));
      ay += bf2f((u16)(v[j]>>16));
    }
  }
  for (; i<e; i++){
    u32 v=*reinterpret_cast<const u32*>(g+(size_t)colv[i]*HD+off);
    ax += bf2f((u16)(v&0xffffu)); ay += bf2f((u16)(v>>16));
  }

  float dv = dinv[node];
  float rx = fmaxf(fmaf(dv, ax, bias[off]),   0.f);
  float ry = fmaxf(fmaf(dv, ay, bias[off+1]), 0.f);
  *reinterpret_cast<u32*>(h + (size_t)node*HD + off) = (u32)f2bf(rx) | ((u32)f2bf(ry)<<16);
}

// ---- global_add_pool, sorted path: one block per graph, no atomics --------
__device__ __forceinline__ int lowerb(const void* a, int is32, int n, int key){
  int lo=0, hi=n;
  while (lo<hi){
    int mid=(lo+hi)>>1;
    if (idx_at(a, mid, is32) < key) lo=mid+1; else hi=mid;
  }
  return lo;
}

__global__ __launch_bounds__(128) void k_pool_sorted(
    const u16* __restrict__ h, const void* __restrict__ batch,
    const int* __restrict__ bflag, const int* __restrict__ sflag,
    float* __restrict__ pooled, int n)
{
  if (*sflag) return;                       // unsorted -> atomic path handles it
  int gid = blockIdx.x, t = threadIdx.x;    // 128 threads, one feature each
  int is32 = *bflag;
  int lo = lowerb(batch, is32, n, gid), hi = lowerb(batch, is32, n, gid+1);
  float acc = 0.f;
  for (int i=lo;i<hi;i++) acc += bf2f(h[(size_t)i*HD + t]);
  pooled[(size_t)gid*HD + t] = acc;
}

// ---- global_add_pool, fallback: atomicAdd per node (any ordering) ---------
__global__ __launch_bounds__(256) void k_pool_atomic(
    const u16* __restrict__ h, const void* __restrict__ batch,
    const int* __restrict__ bflag, const int* __restrict__ sflag,
    float* __restrict__ pooled, int n)
{
  if (!*sflag) return;                      // sorted path already did it
  int node = blockIdx.x*4 + (threadIdx.x>>6);
  if (node >= n) return;
  int lane = threadIdx.x & 63;
  int off = lane*2;
  int g = idx_at(batch, node, *bflag);
  u32 v = *reinterpret_cast<const u32*>(h + (size_t)node*HD + off);
  atomicAdd(&pooled[(size_t)g*HD + off],     bf2f((u16)(v&0xffffu)));
  atomicAdd(&pooled[(size_t)g*HD + off + 1], bf2f((u16)(v>>16)));
}

// ---- final linear: out = pooled @ Wl + bl  (FP32 output) ------------------
__global__ void k_final(const float* __restrict__ pooled, const float* __restrict__ Wl,
                        const float* __restrict__ bl, float* __restrict__ out){
  int gid = blockIdx.x, t = threadIdx.x;   // 64 threads
  float acc = bl[t];
  const float* p = pooled + gid*HD;
  #pragma unroll 8
  for (int k=0;k<HD;k++) acc = fmaf(p[k], Wl[k*OUTD + t], acc);
  out[gid*OUTD + t] = acc;
}

extern "C" void kernel_launch(void* const* d_in, const int* in_sizes, int n_in,
                              void* d_out, int out_size, void* d_ws, size_t ws_size,
                              hipStream_t stream)
{
  const float* x   = (const float*)d_in[0];
  const void*  ei  = d_in[1];
  const void*  bat = d_in[2];
  const float* W1  = (const float*)d_in[3];
  const float* b1  = (const float*)d_in[4];
  const float* W2  = (const float*)d_in[5];
  const float* b2  = (const float*)d_in[6];
  const float* Wl  = (const float*)d_in[7];
  const float* bl  = (const float*)d_in[8];
  float* out = (float*)d_out;

  int N = in_sizes[0] / HD;
  int E = in_sizes[1] / 2;
  int G = out_size / OUTD;
  int NCH = (N + 1023) / 1024;
  int nbins = (N + (1<<BIN_SHIFT) - 1) >> BIN_SHIFT;

  char* w = (char*)d_ws;
  size_t o = 0;
  auto alloc = [&](size_t b){ void* p = w + o; o += (b + 255) & ~(size_t)255; return p; };
  int*   cnt     = (int*)  alloc((size_t)N*4);
  int*   row_ptr = (int*)  alloc((size_t)(N+1)*4);
  int*   cursor  = (int*)  alloc((size_t)N*4);
  int*   csum    = (int*)  alloc((size_t)NCH*4);
  int*   colv    = (int*)  alloc((size_t)E*4);
  u64*   pairs   = (u64*)  alloc((size_t)E*8);
  int*   bincur  = (int*)  alloc((size_t)nbins*4);
  float* dinv    = (float*)alloc((size_t)N*4);
  u16*   gbuf    = (u16*)  alloc((size_t)N*HD*2);
  u16*   hbuf    = (u16*)  alloc((size_t)N*HD*2);
  float* pooled  = (float*)alloc((size_t)G*HD*4);
  int*   eflag   = (int*)  alloc(256);
  int*   bflag   = (int*)  alloc(256);
  int*   sflag   = (int*)  alloc(256);
  (void)n_in;

  if (o > ws_size){
    k_zero_out<<<(out_size+255)/256, 256, 0, stream>>>(out, out_size);
    return;
  }

  // detect int32 vs int64 index delivery (flag: 1 = int32, 0 = int64)
  int npairs_e = 4096; if (npairs_e > E) npairs_e = E;
  int npairs_b = 4096; if (npairs_b > N/2) npairs_b = N/2;
  (void)hipMemsetAsync(eflag, 0, 4, stream);
  (void)hipMemsetAsync(bflag, 0, 4, stream);
  (void)hipMemsetAsync(sflag, 0, 4, stream);
  k_detect <<<(npairs_e+255)/256, 256, 0, stream>>>((const u32*)ei, eflag, npairs_e);
  k_detect <<<(npairs_b+255)/256, 256, 0, stream>>>((const u32*)bat, bflag, npairs_b);
  k_check_sorted<<<(N+255)/256, 256, 0, stream>>>(bat, bflag, sflag, N);

  // CSR build: count -> scan -> two-phase binned fill
  (void)hipMemsetAsync(cnt, 0, (size_t)N*4, stream);
  k_count      <<<(E+255)/256, 256, 0, stream>>>(ei, eflag, cnt, E);
  k_chunk_sums <<<NCH, 256, 0, stream>>>(cnt, csum, N);
  k_scan_totals<<<1, 256, 0, stream>>>(csum, NCH);
  k_scan_chunks<<<NCH, 256, 0, stream>>>(cnt, csum, row_ptr, cursor, dinv, N, E);
  k_init_bincur<<<(nbins+255)/256, 256, 0, stream>>>(row_ptr, bincur, nbins, N);
  k_bin_edges  <<<(E+255)/256, 256, 0, stream>>>(ei, eflag, bincur, pairs, E);
  k_scatter_bins<<<nbins, 256, 0, stream>>>(pairs, row_ptr, cursor, colv, N);

  // layer 1
  k_gemm_scale<float><<<512, 256, 0, stream>>>(x, W1, dinv, gbuf, N);
  k_aggregate <<<(N+3)/4, 256, 0, stream>>>(gbuf, row_ptr, colv, dinv, b1, hbuf, N);
  // layer 2
  k_gemm_scale<u16>  <<<512, 256, 0, stream>>>(hbuf, W2, dinv, gbuf, N);
  k_aggregate <<<(N+3)/4, 256, 0, stream>>>(gbuf, row_ptr, colv, dinv, b2, hbuf, N);
  // pool: sorted fast path + atomic fallback (exactly one does work)
  (void)hipMemsetAsync(pooled, 0, (size_t)G*HD*4, stream);
  k_pool_sorted<<<G, 128, 0, stream>>>(hbuf, bat, bflag, sflag, pooled, N);
  k_pool_atomic<<<(N+3)/4, 256, 0, stream>>>(hbuf, bat, bflag, sflag, pooled, N);
  k_final      <<<G, OUTD, 0, stream>>>(pooled, Wl, bl, out);
}

// Round 11
// 572.729 us; speedup vs baseline: 1.6117x; 1.6117x over previous
//
#include <hip/hip_runtime.h>
#include <hip/hip_bf16.h>

typedef unsigned short u16;
typedef unsigned int   u32;
typedef unsigned long long u64;
typedef long long      i64;
typedef __attribute__((ext_vector_type(8))) short short8;  // 8 bf16 raw
typedef __attribute__((ext_vector_type(4))) float f32x4;

#define HD 128   // hidden / input feature dim
#define OUTD 64  // final output dim
#define FILL_NB 8        // dst buckets == XCD count
#define FILL_CHUNK 16384 // edges per block-chunk in bucketed fill

__device__ __forceinline__ float bf2f(u16 u){ union{u32 i; float f;} x; x.i=((u32)u)<<16; return x.f; }
__device__ __forceinline__ u16 f2bf(float f){ __hip_bfloat16 h=__float2bfloat16(f); return *reinterpret_cast<u16*>(&h); }

// 8-element bf16 fragment loader: fp32 source converts, bf16 source is direct.
__device__ __forceinline__ short8 load8(const float* p){
  f32x4 lo = *reinterpret_cast<const f32x4*>(p);
  f32x4 hi = *reinterpret_cast<const f32x4*>(p + 4);
  short8 r;
  #pragma unroll
  for (int j=0;j<4;j++){ r[j]=(short)f2bf(lo[j]); r[4+j]=(short)f2bf(hi[j]); }
  return r;
}
__device__ __forceinline__ short8 load8(const u16* p){
  return *reinterpret_cast<const short8*>(p);
}

// index fetch that handles int32-vs-int64 delivery (flag: 1 = int32, 0 = int64)
__device__ __forceinline__ int idx_at(const void* p, int i, int is32){
  return is32 ? ((const int*)p)[i] : (int)((const i64*)p)[i];
}

// ---- combined flags: edge-idx dtype, batch dtype, batch sortedness --------
// flags[0]=eflag(1=int32), flags[1]=bflag, flags[2]=sflag(1=unsorted)
__global__ void k_flags(const u32* __restrict__ ei, const void* __restrict__ batch,
                        int* __restrict__ flags, int npairs_e, int npairs_b, int n){
  int i = blockIdx.x*256 + threadIdx.x;
  if (i < npairs_e && ei[2*i+1] != 0) atomicOr(&flags[0], 1);
  const u32* bw = (const u32*)batch;
  if (i < npairs_b && bw[2*i+1] != 0) atomicOr(&flags[1], 1);
  // sortedness under both dtype hypotheses: check the one that applies later
  if (i < n-1){
    // int32 view
    const int* b32 = (const int*)batch;
    if (b32[i] > b32[i+1]) atomicOr(&flags[4], 1);
    // int64 view
    const i64* b64 = (const i64*)batch;
    if (i < n-1 && b64[i] > b64[i+1]) atomicOr(&flags[8], 1);
  }
}
// resolve sflag after dtype known (single tiny kernel)
__global__ void k_resolve_sflag(int* flags){
  if (threadIdx.x==0) flags[2] = flags[1] ? flags[4] : flags[8];
}

// ---- zero-fill output (ws-too-small fallback signal) ----------------------
__global__ void k_zero_out(float* __restrict__ out, int n){
  int i = blockIdx.x*256 + threadIdx.x;
  if (i < n) out[i] = 0.f;
}

// ---- CSR build ------------------------------------------------------------
__global__ void k_count(const void* __restrict__ ei, const int* __restrict__ flags,
                        int* __restrict__ cnt, int E){
  int e = blockIdx.x*256 + threadIdx.x;
  if (e < E){
    int d = idx_at(ei, E + e, flags[0]);   // dst = row 1
    atomicAdd(&cnt[d], 1);
  }
}

__global__ void k_chunk_sums(const int* __restrict__ cnt, int* __restrict__ csum, int n){
  __shared__ int sd[256];
  int c=blockIdx.x, t=threadIdx.x;
  int base=c*1024+t*4, s=0;
  #pragma unroll
  for (int k=0;k<4;k++){ int i=base+k; if(i<n) s+=cnt[i]; }
  sd[t]=s; __syncthreads();
  for (int o=128;o>0;o>>=1){ if(t<o) sd[t]+=sd[t+o]; __syncthreads(); }
  if (t==0) csum[c]=sd[0];
}

// one-block exclusive scan of chunk totals (m <= 1024)
__global__ void k_scan_totals(int* csum, int m){
  __shared__ int sd[256];
  int t = threadIdx.x;
  int v[4]; int s=0;
  #pragma unroll
  for (int k=0;k<4;k++){ int i=t*4+k; v[k]=(i<m)?csum[i]:0; s+=v[k]; }
  sd[t]=s; __syncthreads();
  for (int o=1;o<256;o<<=1){ int x=(t>=o)?sd[t-o]:0; __syncthreads(); sd[t]+=x; __syncthreads(); }
  int pre = (t>0)?sd[t-1]:0;
  #pragma unroll
  for (int k=0;k<4;k++){ int i=t*4+k; if(i<m){ int vv=v[k]; csum[i]=pre; pre+=vv; } }
}

__global__ void k_scan_chunks(const int* __restrict__ cnt, const int* __restrict__ csum,
                              int* __restrict__ row_ptr, int* __restrict__ cursor,
                              float* __restrict__ dinv, int n, int total){
  __shared__ int sd[256];
  int c=blockIdx.x, t=threadIdx.x;
  int base=c*1024+t*4;
  int v[4], s=0;
  #pragma unroll
  for (int k=0;k<4;k++){ int i=base+k; v[k]=(i<n)?cnt[i]:0; s+=v[k]; }
  sd[t]=s; __syncthreads();
  for (int o=1;o<256;o<<=1){ int x=(t>=o)?sd[t-o]:0; __syncthreads(); sd[t]+=x; __syncthreads(); }
  int pre = csum[c] + ((t>0)?sd[t-1]:0);
  #pragma unroll
  for (int k=0;k<4;k++){
    int i=base+k;
    if (i<n){
      row_ptr[i]=pre; cursor[i]=pre;
      dinv[i]=rsqrtf((float)(v[k]+1));   // +1 self-loop; always >0
      pre+=v[k];
    }
  }
  if (c==0 && t==0) row_ptr[n]=total;
}

// ---- bucketed CSR fill: bucket = blockIdx%8 tracks XCD round-robin --------
// (r9: 85 us. r10's 782-bin cursor variant hit atomic-line serialization:
//  1.6M atomics / 49 cache lines ~= 400 us. Per-node cursors are safe.)
__global__ __launch_bounds__(256) void k_fill_bucketed(
    const void* __restrict__ ei, const int* __restrict__ flags,
    int* __restrict__ cursor, int* __restrict__ colv, int E, int N)
{
  int bucket = blockIdx.x % FILL_NB;
  int chunk  = blockIdx.x / FILL_NB;
  int lo = (int)((i64)bucket     * N / FILL_NB);
  int hi = (int)((i64)(bucket+1) * N / FILL_NB);
  int base = chunk * FILL_CHUNK;
  int end  = base + FILL_CHUNK; if (end > E) end = E;
  int is32 = flags[0];
  for (int e = base + threadIdx.x; e < end; e += 256){
    int d = idx_at(ei, E + e, is32);
    if (d >= lo && d < hi){
      int s = idx_at(ei, e, is32);
      int pos = atomicAdd(&cursor[d], 1);
      colv[pos] = s;
    }
  }
}

// ---- MFMA GEMM with dinv-scale epilogue: G = dinv ⊙ (X @ W) ---------------
template <typename TIN>
__global__ __launch_bounds__(256) void k_gemm_scale(
    const TIN* __restrict__ X, const float* __restrict__ W,
    const float* __restrict__ dinv, u16* __restrict__ Gout, int nrows)
{
  int lane = threadIdx.x & 63;
  int wv   = threadIdx.x >> 6;
  int n    = lane & 15, quad = lane >> 4;

  short8 bf[8][4];
  #pragma unroll
  for (int t=0;t<8;t++)
    #pragma unroll
    for (int c=0;c<4;c++)
      #pragma unroll
      for (int j=0;j<8;j++)
        bf[t][c][j] = (short)f2bf(W[(c*32 + quad*8 + j)*HD + t*16 + n]);

  int ntiles = (nrows+15)>>4;
  int stride = gridDim.x*4;
  for (int tile = blockIdx.x*4 + wv; tile < ntiles; tile += stride){
    int ra = tile*16 + n;                 // lane's A row (m = lane&15)
    if (ra >= nrows) ra = nrows-1;
    const TIN* xp = X + (size_t)ra*HD + quad*8;
    short8 a[4];
    #pragma unroll
    for (int c=0;c<4;c++) a[c] = load8(xp + c*32);

    f32x4 acc[8];
    #pragma unroll
    for (int t=0;t<8;t++) acc[t] = (f32x4){0.f,0.f,0.f,0.f};
    #pragma unroll
    for (int c=0;c<4;c++)
      #pragma unroll
      for (int t=0;t<8;t++)
        acc[t] = __builtin_amdgcn_mfma_f32_16x16x32_bf16(a[c], bf[t][c], acc[t], 0,0,0);

    float dv[4]; int rw[4];
    #pragma unroll
    for (int r=0;r<4;r++){
      int row = tile*16 + quad*4 + r;
      rw[r]=row; dv[r]=(row<nrows)?dinv[row]:0.f;
    }
    #pragma unroll
    for (int t=0;t<8;t++)
      #pragma unroll
      for (int r=0;r<4;r++){
        int row = rw[r];
        if (row < nrows)
          Gout[(size_t)row*HD + t*16 + n] = f2bf(dv[r]*acc[t][r]);
      }
  }
}

// ---- aggregation: h[i] = relu(dinv[i]*(g[i] + sum_{src} g[src]) + b) ------
// one wave per node; lane handles 2 features; unroll-8 for gather MLP.
__global__ __launch_bounds__(256) void k_aggregate(
    const u16* __restrict__ g, const int* __restrict__ row_ptr,
    const int* __restrict__ colv, const float* __restrict__ dinv,
    const float* __restrict__ bias, u16* __restrict__ h, int n)
{
  int node = blockIdx.x*4 + (threadIdx.x>>6);
  if (node >= n) return;
  int lane = threadIdx.x & 63;
  int off = lane*2;

  u32 u = *reinterpret_cast<const u32*>(g + (size_t)node*HD + off);   // self-loop term
  float ax = bf2f((u16)(u&0xffffu)), ay = bf2f((u16)(u>>16));

  int s = row_ptr[node], e = row_ptr[node+1];
  int i = s;
  for (; i+8<=e; i+=8){
    u32 v[8];
    #pragma unroll
    for (int j=0;j<8;j++){
      int sj = colv[i+j];
      v[j] = *reinterpret_cast<const u32*>(g+(size_t)sj*HD+off);
    }
    #pragma unroll
    for (int j=0;j<8;j++){
      ax += bf2f((u16)(v[j]&0xffffu));
      ay += bf2f((u16)(v[j]>>16));
    }
  }
  for (; i<e; i++){
    u32 v=*reinterpret_cast<const u32*>(g+(size_t)colv[i]*HD+off);
    ax += bf2f((u16)(v&0xffffu)); ay += bf2f((u16)(v>>16));
  }

  float dv = dinv[node];
  float rx = fmaxf(fmaf(dv, ax, bias[off]),   0.f);
  float ry = fmaxf(fmaf(dv, ay, bias[off+1]), 0.f);
  *reinterpret_cast<u32*>(h + (size_t)node*HD + off) = (u32)f2bf(rx) | ((u32)f2bf(ry)<<16);
}

// ---- global_add_pool, sorted path: one block per graph, no atomics --------
__device__ __forceinline__ int lowerb(const void* a, int is32, int n, int key){
  int lo=0, hi=n;
  while (lo<hi){
    int mid=(lo+hi)>>1;
    if (idx_at(a, mid, is32) < key) lo=mid+1; else hi=mid;
  }
  return lo;
}

__global__ __launch_bounds__(128) void k_pool_sorted(
    const u16* __restrict__ h, const void* __restrict__ batch,
    const int* __restrict__ flags, float* __restrict__ pooled, int n)
{
  if (flags[2]) return;                     // unsorted -> atomic path handles it
  int gid = blockIdx.x, t = threadIdx.x;    // 128 threads, one feature each
  int is32 = flags[1];
  int lo = lowerb(batch, is32, n, gid), hi = lowerb(batch, is32, n, gid+1);
  float acc = 0.f;
  for (int i=lo;i<hi;i++) acc += bf2f(h[(size_t)i*HD + t]);
  pooled[(size_t)gid*HD + t] = acc;
}

// ---- global_add_pool, fallback: atomicAdd per node (any ordering) ---------
__global__ __launch_bounds__(256) void k_pool_atomic(
    const u16* __restrict__ h, const void* __restrict__ batch,
    const int* __restrict__ flags, float* __restrict__ pooled, int n)
{
  if (!flags[2]) return;                    // sorted path already did it
  int node = blockIdx.x*4 + (threadIdx.x>>6);
  if (node >= n) return;
  int lane = threadIdx.x & 63;
  int off = lane*2;
  int g = idx_at(batch, node, flags[1]);
  u32 v = *reinterpret_cast<const u32*>(h + (size_t)node*HD + off);
  atomicAdd(&pooled[(size_t)g*HD + off],     bf2f((u16)(v&0xffffu)));
  atomicAdd(&pooled[(size_t)g*HD + off + 1], bf2f((u16)(v>>16)));
}

// ---- final linear: out = pooled @ Wl + bl  (FP32 output) ------------------
__global__ void k_final(const float* __restrict__ pooled, const float* __restrict__ Wl,
                        const float* __restrict__ bl, float* __restrict__ out){
  int gid = blockIdx.x, t = threadIdx.x;   // 64 threads
  float acc = bl[t];
  const float* p = pooled + gid*HD;
  #pragma unroll 8
  for (int k=0;k<HD;k++) acc = fmaf(p[k], Wl[k*OUTD + t], acc);
  out[gid*OUTD + t] = acc;
}

extern "C" void kernel_launch(void* const* d_in, const int* in_sizes, int n_in,
                              void* d_out, int out_size, void* d_ws, size_t ws_size,
                              hipStream_t stream)
{
  const float* x   = (const float*)d_in[0];
  const void*  ei  = d_in[1];
  const void*  bat = d_in[2];
  const float* W1  = (const float*)d_in[3];
  const float* b1  = (const float*)d_in[4];
  const float* W2  = (const float*)d_in[5];
  const float* b2  = (const float*)d_in[6];
  const float* Wl  = (const float*)d_in[7];
  const float* bl  = (const float*)d_in[8];
  float* out = (float*)d_out;

  int N = in_sizes[0] / HD;
  int E = in_sizes[1] / 2;
  int G = out_size / OUTD;
  int NCH = (N + 1023) / 1024;

  char* w = (char*)d_ws;
  size_t o = 0;
  auto alloc = [&](size_t b){ void* p = w + o; o += (b + 255) & ~(size_t)255; return p; };
  int*   cnt     = (int*)  alloc((size_t)N*4);
  int*   row_ptr = (int*)  alloc((size_t)(N+1)*4);
  int*   cursor  = (int*)  alloc((size_t)N*4);
  int*   csum    = (int*)  alloc((size_t)NCH*4);
  int*   colv    = (int*)  alloc((size_t)E*4);
  float* dinv    = (float*)alloc((size_t)N*4);
  u16*   gbuf    = (u16*)  alloc((size_t)N*HD*2);
  u16*   hbuf    = (u16*)  alloc((size_t)N*HD*2);
  float* pooled  = (float*)alloc((size_t)G*HD*4);
  int*   flags   = (int*)  alloc(256);
  (void)n_in;

  if (o > ws_size){
    k_zero_out<<<(out_size+255)/256, 256, 0, stream>>>(out, out_size);
    return;
  }

  // flags: [0]=edge int32?, [1]=batch int32?, [2]=batch unsorted?, [4]/[8] raw
  int npairs_e = 4096; if (npairs_e > E) npairs_e = E;
  int npairs_b = 4096; if (npairs_b > N/2) npairs_b = N/2;
  (void)hipMemsetAsync(flags, 0, 64, stream);
  int nf = N-1; if (npairs_e > nf) nf = npairs_e; if (npairs_b > nf) nf = npairs_b;
  k_flags        <<<(nf+255)/256, 256, 0, stream>>>((const u32*)ei, bat, flags, npairs_e, npairs_b, N);
  k_resolve_sflag<<<1, 64, 0, stream>>>(flags);

  // CSR build: count -> scan -> bucketed fill
  (void)hipMemsetAsync(cnt, 0, (size_t)N*4, stream);
  k_count      <<<(E+255)/256, 256, 0, stream>>>(ei, flags, cnt, E);
  k_chunk_sums <<<NCH, 256, 0, stream>>>(cnt, csum, N);
  k_scan_totals<<<1, 256, 0, stream>>>(csum, NCH);
  k_scan_chunks<<<NCH, 256, 0, stream>>>(cnt, csum, row_ptr, cursor, dinv, N, E);
  int fill_chunks = (E + FILL_CHUNK - 1) / FILL_CHUNK;
  k_fill_bucketed<<<fill_chunks*FILL_NB, 256, 0, stream>>>(ei, flags, cursor, colv, E, N);

  // layer 1
  k_gemm_scale<float><<<512, 256, 0, stream>>>(x, W1, dinv, gbuf, N);
  k_aggregate <<<(N+3)/4, 256, 0, stream>>>(gbuf, row_ptr, colv, dinv, b1, hbuf, N);
  // layer 2
  k_gemm_scale<u16>  <<<512, 256, 0, stream>>>(hbuf, W2, dinv, gbuf, N);
  k_aggregate <<<(N+3)/4, 256, 0, stream>>>(gbuf, row_ptr, colv, dinv, b2, hbuf, N);
  // pool: sorted fast path + atomic fallback (exactly one does work)
  (void)hipMemsetAsync(pooled, 0, (size_t)G*HD*4, stream);
  k_pool_sorted<<<G, 128, 0, stream>>>(hbuf, bat, flags, pooled, N);
  k_pool_atomic<<<(N+3)/4, 256, 0, stream>>>(hbuf, bat, flags, pooled, N);
  k_final      <<<G, OUTD, 0, stream>>>(pooled, Wl, bl, out);
}

// Round 13
// 556.134 us; speedup vs baseline: 1.6598x; 1.0298x over previous
//
#include <hip/hip_runtime.h>
#include <hip/hip_bf16.h>

typedef unsigned short u16;
typedef unsigned int   u32;
typedef unsigned long long u64;
typedef long long      i64;
typedef __attribute__((ext_vector_type(8))) short short8;  // 8 bf16 raw
typedef __attribute__((ext_vector_type(4))) float f32x4;

#define HD 128   // hidden / input feature dim
#define OUTD 64  // final output dim
#define BSH 8            // bucket shift: 256 nodes per bucket (power of 2!)
#define NBKT_MAX 512     // max buckets (N <= 128K)
#define PCHUNK 4096      // edges per block in pass 1
#define GCUR_STRIDE 16   // ints; 64 B padding to avoid atomic line contention

__device__ __forceinline__ float bf2f(u16 u){ union{u32 i; float f;} x; x.i=((u32)u)<<16; return x.f; }
__device__ __forceinline__ u16 f2bf(float f){ __hip_bfloat16 h=__float2bfloat16(f); return *reinterpret_cast<u16*>(&h); }

// 8-element bf16 fragment loader: fp32 source converts, bf16 source is direct.
__device__ __forceinline__ short8 load8(const float* p){
  f32x4 lo = *reinterpret_cast<const f32x4*>(p);
  f32x4 hi = *reinterpret_cast<const f32x4*>(p + 4);
  short8 r;
  #pragma unroll
  for (int j=0;j<4;j++){ r[j]=(short)f2bf(lo[j]); r[4+j]=(short)f2bf(hi[j]); }
  return r;
}
__device__ __forceinline__ short8 load8(const u16* p){
  return *reinterpret_cast<const short8*>(p);
}

// index fetch that handles int32-vs-int64 delivery (flag: 1 = int32, 0 = int64)
__device__ __forceinline__ int idx_at(const void* p, int i, int is32){
  return is32 ? ((const int*)p)[i] : (int)((const i64*)p)[i];
}

// ---- dtype flags only (bounded reads: no OOB under either delivery) -------
// flags[0]=edge int32?, flags[1]=batch int32?, flags[2]=batch unsorted?
__global__ void k_flags(const u32* __restrict__ ei, const u32* __restrict__ bw,
                        int* __restrict__ flags, int npairs_e, int npairs_b){
  int i = blockIdx.x*256 + threadIdx.x;
  if (i < npairs_e && ei[2*i+1] != 0) atomicOr(&flags[0], 1);
  if (i < npairs_b && bw[2*i+1] != 0) atomicOr(&flags[1], 1);
}

// ---- sortedness check AFTER dtype resolution (reads bounded by true size) -
__global__ void k_check_sorted(const void* __restrict__ batch, int* __restrict__ flags, int n){
  int i = blockIdx.x*256 + threadIdx.x;
  if (i < n-1){
    int is32 = flags[1];
    if (idx_at(batch, i, is32) > idx_at(batch, i+1, is32)) atomicOr(&flags[2], 1);
  }
}

// ---- zero-fill output (ws-too-small fallback signal) ----------------------
__global__ void k_zero_out(float* __restrict__ out, int n){
  int i = blockIdx.x*256 + threadIdx.x;
  if (i < n) out[i] = 0.f;
}

// ---- CSR build ------------------------------------------------------------
__global__ void k_count(const void* __restrict__ ei, const int* __restrict__ flags,
                        int* __restrict__ cnt, int E){
  int e = blockIdx.x*256 + threadIdx.x;
  if (e < E){
    int d = idx_at(ei, E + e, flags[0]);   // dst = row 1
    atomicAdd(&cnt[d], 1);
  }
}

__global__ void k_chunk_sums(const int* __restrict__ cnt, int* __restrict__ csum, int n){
  __shared__ int sd[256];
  int c=blockIdx.x, t=threadIdx.x;
  int base=c*1024+t*4, s=0;
  #pragma unroll
  for (int k=0;k<4;k++){ int i=base+k; if(i<n) s+=cnt[i]; }
  sd[t]=s; __syncthreads();
  for (int o=128;o>0;o>>=1){ if(t<o) sd[t]+=sd[t+o]; __syncthreads(); }
  if (t==0) csum[c]=sd[0];
}

// one-block exclusive scan of chunk totals (m <= 1024)
__global__ void k_scan_totals(int* csum, int m){
  __shared__ int sd[256];
  int t = threadIdx.x;
  int v[4]; int s=0;
  #pragma unroll
  for (int k=0;k<4;k++){ int i=t*4+k; v[k]=(i<m)?csum[i]:0; s+=v[k]; }
  sd[t]=s; __syncthreads();
  for (int o=1;o<256;o<<=1){ int x=(t>=o)?sd[t-o]:0; __syncthreads(); sd[t]+=x; __syncthreads(); }
  int pre = (t>0)?sd[t-1]:0;
  #pragma unroll
  for (int k=0;k<4;k++){ int i=t*4+k; if(i<m){ int vv=v[k]; csum[i]=pre; pre+=vv; } }
}

__global__ void k_scan_chunks(const int* __restrict__ cnt, const int* __restrict__ csum,
                              int* __restrict__ row_ptr, int* __restrict__ cursor,
                              float* __restrict__ dinv, int n, int total){
  __shared__ int sd[256];
  int c=blockIdx.x, t=threadIdx.x;
  int base=c*1024+t*4;
  int v[4], s=0;
  #pragma unroll
  for (int k=0;k<4;k++){ int i=base+k; v[k]=(i<n)?cnt[i]:0; s+=v[k]; }
  sd[t]=s; __syncthreads();
  for (int o=1;o<256;o<<=1){ int x=(t>=o)?sd[t-o]:0; __syncthreads(); sd[t]+=x; __syncthreads(); }
  int pre = csum[c] + ((t>0)?sd[t-1]:0);
  #pragma unroll
  for (int k=0;k<4;k++){
    int i=base+k;
    if (i<n){
      row_ptr[i]=pre; cursor[i]=pre;
      dinv[i]=rsqrtf((float)(v[k]+1));   // +1 self-loop; always >0
      pre+=v[k];
    }
  }
  if (c==0 && t==0) row_ptr[n]=total;
}

// ---- partition fill, phase 0: init padded bucket cursors from row_ptr -----
// bucket(d) = d>>BSH  <->  region b = [row_ptr[b<<BSH], row_ptr[(b+1)<<BSH])
// (power-of-2 split: bucket function and region boundaries EXACTLY consistent;
//  r12's floor/ceil mismatch left poison slots -> GPU fault)
__global__ void k_init_gcur(const int* __restrict__ row_ptr, int* __restrict__ gcur,
                            int nbins, int N){
  int b = blockIdx.x*256 + threadIdx.x;
  if (b < nbins) gcur[b*GCUR_STRIDE] = row_ptr[b<<BSH];
}

// ---- phase 1: LDS-staged partition of edges into dst-buckets --------------
// Block-level reservations only (padded cursors, ~1 atomic/block/bucket);
// staged pairs flushed as coalesced runs.
__global__ __launch_bounds__(256) void k_part1(
    const void* __restrict__ ei, const int* __restrict__ flags,
    int* __restrict__ gcur, u64* __restrict__ pairs, int E)
{
  __shared__ int hist[NBKT_MAX];
  __shared__ int soff[NBKT_MAX];
  __shared__ int gb[NBKT_MAX];
  __shared__ int scant[256];
  __shared__ u64 stage[PCHUNK];
  __shared__ u16 sbkt[PCHUNK];

  int tid = threadIdx.x;
  hist[tid]=0; hist[tid+256]=0;
  __syncthreads();

  int base = blockIdx.x*PCHUNK;
  int is32 = flags[0];
  int d[PCHUNK/256], s[PCHUNK/256];
  #pragma unroll
  for (int k=0;k<PCHUNK/256;k++){
    int e = base + k*256 + tid;
    if (e < E){
      d[k]=idx_at(ei,E+e,is32); s[k]=idx_at(ei,e,is32);
      atomicAdd(&hist[d[k]>>BSH],1);
    } else d[k]=-1;
  }
  __syncthreads();

  // scan 512 buckets with 256 threads (2 each)
  int a0=hist[2*tid], a1=hist[2*tid+1];
  scant[tid]=a0+a1; __syncthreads();
  for (int o=1;o<256;o<<=1){ int x=(tid>=o)?scant[tid-o]:0; __syncthreads(); scant[tid]+=x; __syncthreads(); }
  int pre = (tid>0)?scant[tid-1]:0;
  soff[2*tid]=pre; soff[2*tid+1]=pre+a0;
  // reserve global runs (block-level atomics, 64 B-padded cursors)
  if (a0) gb[2*tid]   = atomicAdd(&gcur[(2*tid)*GCUR_STRIDE],   a0); else gb[2*tid]=0;
  if (a1) gb[2*tid+1] = atomicAdd(&gcur[(2*tid+1)*GCUR_STRIDE], a1); else gb[2*tid+1]=0;
  hist[2*tid]=0; hist[2*tid+1]=0;
  __syncthreads();

  // scatter into LDS stage ordered by bucket
  #pragma unroll
  for (int k=0;k<PCHUNK/256;k++){
    if (d[k]>=0){
      int b = d[k]>>BSH;
      int loc = soff[b] + atomicAdd(&hist[b],1);
      stage[loc] = ((u64)(u32)d[k] << 32) | (u32)s[k];
      sbkt[loc] = (u16)b;
    }
  }
  __syncthreads();

  // coalesced flush: consecutive slots of a bucket -> consecutive global pairs
  int cnt_edges = E - base; if (cnt_edges > PCHUNK) cnt_edges = PCHUNK;
  for (int i=tid; i<cnt_edges; i+=256){
    int b = sbkt[i];
    pairs[(size_t)gb[b] + (i - soff[b])] = stage[i];
  }
}

// ---- phase 2: per-bucket exact scatter (block-private colv window) --------
__global__ __launch_bounds__(256) void k_part2(
    const u64* __restrict__ pairs, const int* __restrict__ row_ptr,
    int* __restrict__ cursor, int* __restrict__ colv, int N)
{
  int b = blockIdx.x;
  int n0 = b<<BSH;
  int n1 = (b+1)<<BSH; if (n1 > N) n1 = N;
  int lo = row_ptr[n0], hi = row_ptr[n1];
  for (int i = lo + threadIdx.x; i < hi; i += 256){
    u64 p = pairs[i];
    int s = (int)(u32)(p & 0xffffffffu), d = (int)(u32)(p >> 32);
    int pos = atomicAdd(&cursor[d], 1);
    colv[pos] = s;
  }
}

// ---- MFMA GEMM with dinv-scale epilogue: G = dinv ⊙ (X @ W) ---------------
template <typename TIN>
__global__ __launch_bounds__(256) void k_gemm_scale(
    const TIN* __restrict__ X, const float* __restrict__ W,
    const float* __restrict__ dinv, u16* __restrict__ Gout, int nrows)
{
  int lane = threadIdx.x & 63;
  int wv   = threadIdx.x >> 6;
  int n    = lane & 15, quad = lane >> 4;

  short8 bf[8][4];
  #pragma unroll
  for (int t=0;t<8;t++)
    #pragma unroll
    for (int c=0;c<4;c++)
      #pragma unroll
      for (int j=0;j<8;j++)
        bf[t][c][j] = (short)f2bf(W[(c*32 + quad*8 + j)*HD + t*16 + n]);

  int ntiles = (nrows+15)>>4;
  int stride = gridDim.x*4;
  for (int tile = blockIdx.x*4 + wv; tile < ntiles; tile += stride){
    int ra = tile*16 + n;                 // lane's A row (m = lane&15)
    if (ra >= nrows) ra = nrows-1;
    const TIN* xp = X + (size_t)ra*HD + quad*8;
    short8 a[4];
    #pragma unroll
    for (int c=0;c<4;c++) a[c] = load8(xp + c*32);

    f32x4 acc[8];
    #pragma unroll
    for (int t=0;t<8;t++) acc[t] = (f32x4){0.f,0.f,0.f,0.f};
    #pragma unroll
    for (int c=0;c<4;c++)
      #pragma unroll
      for (int t=0;t<8;t++)
        acc[t] = __builtin_amdgcn_mfma_f32_16x16x32_bf16(a[c], bf[t][c], acc[t], 0,0,0);

    float dv[4]; int rw[4];
    #pragma unroll
    for (int r=0;r<4;r++){
      int row = tile*16 + quad*4 + r;
      rw[r]=row; dv[r]=(row<nrows)?dinv[row]:0.f;
    }
    #pragma unroll
    for (int t=0;t<8;t++)
      #pragma unroll
      for (int r=0;r<4;r++){
        int row = rw[r];
        if (row < nrows)
          Gout[(size_t)row*HD + t*16 + n] = f2bf(dv[r]*acc[t][r]);
      }
  }
}

// ---- aggregation: h[i] = relu(dinv[i]*(g[i] + sum_{src} g[src]) + b) ------
// one wave per node; lane handles 2 features; at compulsory-miss floor.
__global__ __launch_bounds__(256) void k_aggregate(
    const u16* __restrict__ g, const int* __restrict__ row_ptr,
    const int* __restrict__ colv, const float* __restrict__ dinv,
    const float* __restrict__ bias, u16* __restrict__ h, int n)
{
  int node = blockIdx.x*4 + (threadIdx.x>>6);
  if (node >= n) return;
  int lane = threadIdx.x & 63;
  int off = lane*2;

  u32 u = *reinterpret_cast<const u32*>(g + (size_t)node*HD + off);   // self-loop term
  float ax = bf2f((u16)(u&0xffffu)), ay = bf2f((u16)(u>>16));

  int s = row_ptr[node], e = row_ptr[node+1];
  int i = s;
  for (; i+8<=e; i+=8){
    u32 v[8];
    #pragma unroll
    for (int j=0;j<8;j++){
      int sj = colv[i+j];
      v[j] = *reinterpret_cast<const u32*>(g+(size_t)sj*HD+off);
    }
    #pragma unroll
    for (int j=0;j<8;j++){
      ax += bf2f((u16)(v[j]&0xffffu));
      ay += bf2f((u16)(v[j]>>16));
    }
  }
  for (; i<e; i++){
    u32 v=*reinterpret_cast<const u32*>(g+(size_t)colv[i]*HD+off);
    ax += bf2f((u16)(v&0xffffu)); ay += bf2f((u16)(v>>16));
  }

  float dv = dinv[node];
  float rx = fmaxf(fmaf(dv, ax, bias[off]),   0.f);
  float ry = fmaxf(fmaf(dv, ay, bias[off+1]), 0.f);
  *reinterpret_cast<u32*>(h + (size_t)node*HD + off) = (u32)f2bf(rx) | ((u32)f2bf(ry)<<16);
}

// ---- global_add_pool, sorted path: one block per graph, no atomics --------
__device__ __forceinline__ int lowerb(const void* a, int is32, int n, int key){
  int lo=0, hi=n;
  while (lo<hi){
    int mid=(lo+hi)>>1;
    if (idx_at(a, mid, is32) < key) lo=mid+1; else hi=mid;
  }
  return lo;
}

__global__ __launch_bounds__(128) void k_pool_sorted(
    const u16* __restrict__ h, const void* __restrict__ batch,
    const int* __restrict__ flags, float* __restrict__ pooled, int n)
{
  if (flags[2]) return;                     // unsorted -> atomic path handles it
  int gid = blockIdx.x, t = threadIdx.x;    // 128 threads, one feature each
  int is32 = flags[1];
  int lo = lowerb(batch, is32, n, gid), hi = lowerb(batch, is32, n, gid+1);
  float acc = 0.f;
  for (int i=lo;i<hi;i++) acc += bf2f(h[(size_t)i*HD + t]);
  pooled[(size_t)gid*HD + t] = acc;
}

// ---- global_add_pool, fallback: atomicAdd per node (any ordering) ---------
__global__ __launch_bounds__(256) void k_pool_atomic(
    const u16* __restrict__ h, const void* __restrict__ batch,
    const int* __restrict__ flags, float* __restrict__ pooled, int n)
{
  if (!flags[2]) return;                    // sorted path already did it
  int node = blockIdx.x*4 + (threadIdx.x>>6);
  if (node >= n) return;
  int lane = threadIdx.x & 63;
  int off = lane*2;
  int g = idx_at(batch, node, flags[1]);
  u32 v = *reinterpret_cast<const u32*>(h + (size_t)node*HD + off);
  atomicAdd(&pooled[(size_t)g*HD + off],     bf2f((u16)(v&0xffffu)));
  atomicAdd(&pooled[(size_t)g*HD + off + 1], bf2f((u16)(v>>16)));
}

// ---- final linear: out = pooled @ Wl + bl  (FP32 output) ------------------
__global__ void k_final(const float* __restrict__ pooled, const float* __restrict__ Wl,
                        const float* __restrict__ bl, float* __restrict__ out){
  int gid = blockIdx.x, t = threadIdx.x;   // 64 threads
  float acc = bl[t];
  const float* p = pooled + gid*HD;
  #pragma unroll 8
  for (int k=0;k<HD;k++) acc = fmaf(p[k], Wl[k*OUTD + t], acc);
  out[gid*OUTD + t] = acc;
}

extern "C" void kernel_launch(void* const* d_in, const int* in_sizes, int n_in,
                              void* d_out, int out_size, void* d_ws, size_t ws_size,
                              hipStream_t stream)
{
  const float* x   = (const float*)d_in[0];
  const void*  ei  = d_in[1];
  const void*  bat = d_in[2];
  const float* W1  = (const float*)d_in[3];
  const float* b1  = (const float*)d_in[4];
  const float* W2  = (const float*)d_in[5];
  const float* b2  = (const float*)d_in[6];
  const float* Wl  = (const float*)d_in[7];
  const float* bl  = (const float*)d_in[8];
  float* out = (float*)d_out;

  int N = in_sizes[0] / HD;
  int E = in_sizes[1] / 2;
  int G = out_size / OUTD;
  int NCH = (N + 1023) / 1024;
  int nbins = (N + (1<<BSH) - 1) >> BSH;   // 256 nodes per bin

  char* w = (char*)d_ws;
  size_t o = 0;
  auto alloc = [&](size_t b){ void* p = w + o; o += (b + 255) & ~(size_t)255; return p; };
  int*   cnt     = (int*)  alloc((size_t)N*4);
  int*   row_ptr = (int*)  alloc((size_t)(N+1)*4);
  int*   cursor  = (int*)  alloc((size_t)N*4);
  int*   csum    = (int*)  alloc((size_t)NCH*4);
  int*   colv    = (int*)  alloc((size_t)E*4);
  u64*   pairs   = (u64*)  alloc((size_t)E*8);
  int*   gcur    = (int*)  alloc((size_t)NBKT_MAX*GCUR_STRIDE*4);
  float* dinv    = (float*)alloc((size_t)N*4);
  u16*   gbuf    = (u16*)  alloc((size_t)N*HD*2);
  u16*   hbuf    = (u16*)  alloc((size_t)N*HD*2);
  float* pooled  = (float*)alloc((size_t)G*HD*4);
  int*   flags   = (int*)  alloc(256);
  (void)n_in;

  if (o > ws_size || nbins > NBKT_MAX){
    k_zero_out<<<(out_size+255)/256, 256, 0, stream>>>(out, out_size);
    return;
  }

  // flags: [0]=edge int32?, [1]=batch int32?, [2]=batch unsorted?
  int npairs_e = 4096; if (npairs_e > E) npairs_e = E;
  int npairs_b = 4096; if (npairs_b > N/2) npairs_b = N/2;
  (void)hipMemsetAsync(flags, 0, 64, stream);
  int nf = npairs_e > npairs_b ? npairs_e : npairs_b;
  k_flags       <<<(nf+255)/256, 256, 0, stream>>>((const u32*)ei, (const u32*)bat, flags, npairs_e, npairs_b);
  k_check_sorted<<<(N+255)/256, 256, 0, stream>>>(bat, flags, N);

  // CSR build: count -> scan -> two-pass LDS-staged partition fill
  (void)hipMemsetAsync(cnt, 0, (size_t)N*4, stream);
  k_count      <<<(E+255)/256, 256, 0, stream>>>(ei, flags, cnt, E);
  k_chunk_sums <<<NCH, 256, 0, stream>>>(cnt, csum, N);
  k_scan_totals<<<1, 256, 0, stream>>>(csum, NCH);
  k_scan_chunks<<<NCH, 256, 0, stream>>>(cnt, csum, row_ptr, cursor, dinv, N, E);
  k_init_gcur  <<<(nbins+255)/256, 256, 0, stream>>>(row_ptr, gcur, nbins, N);
  k_part1      <<<(E+PCHUNK-1)/PCHUNK, 256, 0, stream>>>(ei, flags, gcur, pairs, E);
  k_part2      <<<nbins, 256, 0, stream>>>(pairs, row_ptr, cursor, colv, N);

  // layer 1
  k_gemm_scale<float><<<512, 256, 0, stream>>>(x, W1, dinv, gbuf, N);
  k_aggregate <<<(N+3)/4, 256, 0, stream>>>(gbuf, row_ptr, colv, dinv, b1, hbuf, N);
  // layer 2
  k_gemm_scale<u16>  <<<512, 256, 0, stream>>>(hbuf, W2, dinv, gbuf, N);
  k_aggregate <<<(N+3)/4, 256, 0, stream>>>(gbuf, row_ptr, colv, dinv, b2, hbuf, N);
  // pool: sorted fast path + atomic fallback (exactly one does work)
  (void)hipMemsetAsync(pooled, 0, (size_t)G*HD*4, stream);
  k_pool_sorted<<<G, 128, 0, stream>>>(hbuf, bat, flags, pooled, N);
  k_pool_atomic<<<(N+3)/4, 256, 0, stream>>>(hbuf, bat, flags, pooled, N);
  k_final      <<<G, OUTD, 0, stream>>>(pooled, Wl, bl, out);
}